// Round 6
// baseline (364.925 us; speedup 1.0000x reference)
//
#include <hip/hip_runtime.h>

#define N_NODES 100000
#define N_EDGES 1600000
#define D_FEAT  64

#define RSHIFT 8
#define RPB    256                              // rows per bucket
#define NBK    ((N_NODES + RPB - 1) / RPB)      // 391 row-buckets
#define CAP    4608                             // bucket edge capacity
#define EPB    4096                             // edges per bin block
#define KBLK   ((N_EDGES + EPB - 1) / EPB)      // 391 bin blocks
#define OROW   (NBK + 1)

__device__ __forceinline__ float bf2f(unsigned short u) {
  union { unsigned int i; float f; } v; v.i = ((unsigned int)u) << 16; return v.f;
}
__device__ __forceinline__ unsigned short f2bf(float f) {
  union { float f; unsigned int i; } v; v.f = f;
  unsigned int b = v.i;
  return (unsigned short)((b + 0x7FFFu + ((b >> 16) & 1u)) >> 16);  // RNE
}

// ---- x (f32) -> bf16 once; all 3 layers gather 128B rows (1 line/edge) ----
__global__ __launch_bounds__(256) void convert_x(
    const float4* __restrict__ xin, ushort4* __restrict__ xout) {
  int i = blockIdx.x * 256 + threadIdx.x;
  if (i < (N_NODES * D_FEAT / 4)) {
    float4 v = xin[i];
    ushort4 o;
    o.x = f2bf(v.x); o.y = f2bf(v.y); o.z = f2bf(v.z); o.w = f2bf(v.w);
    xout[i] = o;
  }
}

// ---- pass 1: block-local counting sort of 4096 edges by bucket ----
__global__ __launch_bounds__(1024) void bin_edges(
    const int* __restrict__ erow, const int* __restrict__ ecol,
    const float* __restrict__ evals, int2* __restrict__ tmp,
    int* __restrict__ offs) {
  __shared__ int hist[NBK];
  __shared__ int sc[NBK];
  int t = threadIdx.x;
  int k = blockIdx.x;
  if (t < NBK) hist[t] = 0;
  __syncthreads();
  int base = k * EPB;
  int nk = N_EDGES - base; if (nk > EPB) nk = EPB;
  int key[4], vb[4], rk[4], bk[4];
#pragma unroll
  for (int j = 0; j < 4; ++j) {
    int li = j * 1024 + t;
    bk[j] = -1;
    if (li < nk) {
      int e = base + li;
      int r = erow[e];
      key[j] = ((r & (RPB - 1)) << 17) | ecol[e];
      vb[j]  = __float_as_int(evals[e]);
      bk[j]  = r >> RSHIFT;
      rk[j]  = atomicAdd(&hist[bk[j]], 1);
    }
  }
  __syncthreads();
  if (t < NBK) sc[t] = hist[t];
  __syncthreads();
  for (int off = 1; off < NBK; off <<= 1) {
    int u = (t >= off && t < NBK) ? sc[t - off] : 0;
    __syncthreads();
    if (t < NBK) sc[t] += u;
    __syncthreads();
  }
  if (t < NBK) {
    int ex = sc[t] - hist[t];
    sc[t] = ex;
    offs[k * OROW + t] = ex;
  }
  if (t == 0) offs[k * OROW + NBK] = nk;
  __syncthreads();
#pragma unroll
  for (int j = 0; j < 4; ++j) {
    if (bk[j] >= 0) {
      int pos = sc[bk[j]] + rk[j];
      tmp[k * EPB + pos] = make_int2(key[j], vb[j]);
    }
  }
}

// ---- pass 2: one block per row-bucket. WAVE-per-segment reads (coalesced:
// 64 lanes sweep a ~10-edge segment = one 128B line, not 8B x 32KB strides).
__global__ __launch_bounds__(256) void build_csr(
    const int2* __restrict__ tmp, const int* __restrict__ offs,
    int2* __restrict__ edges, int* __restrict__ row_beg,
    int* __restrict__ row_end) {
  __shared__ int hist[RPB];
  __shared__ int cur[RPB];
  int b = blockIdx.x;
  int t = threadIdx.x;
  int wave = t >> 6;
  int lane = t & 63;
  hist[t] = 0;
  __syncthreads();
  // pass A: histogram of local rows
  for (int k = wave; k < KBLK; k += 4) {
    int o0 = offs[k * OROW + b];
    int o1 = offs[k * OROW + b + 1];
    const int2* seg = tmp + k * EPB;
    for (int i = o0 + lane; i < o1; i += 64)
      atomicAdd(&hist[seg[i].x >> 17], 1);
  }
  __syncthreads();
  int v = hist[t];
  cur[t] = v;
  __syncthreads();
  for (int off = 1; off < 256; off <<= 1) {
    int u = (t >= off) ? cur[t - off] : 0;
    __syncthreads();
    cur[t] += u;
    __syncthreads();
  }
  int excl = cur[t] - v;
  int base = b * CAP;
  int gr = b * RPB + t;
  if (gr < N_NODES) {
    row_beg[gr] = base + excl;
    row_end[gr] = base + excl + v;
  }
  __syncthreads();
  cur[t] = excl;
  __syncthreads();
  // pass B: scatter into bucket-local CSR order (L2-resident 36KB window)
  for (int k = wave; k < KBLK; k += 4) {
    int o0 = offs[k * OROW + b];
    int o1 = offs[k * OROW + b + 1];
    const int2* seg = tmp + k * EPB;
    for (int i = o0 + lane; i < o1; i += 64) {
      int2 ed = seg[i];
      int pos = atomicAdd(&cur[ed.x >> 17], 1);
      edges[base + pos] = make_int2(ed.x & 0x1FFFF, ed.y);
    }
  }
}

// ---- SpMM: one row/wave, 4 edges/iter per quarter, bf16 gather, f32 acc ----
// final_mode 0: h_bf[row] = bf16(A.row * xb)
// final_mode 1: out[row] (f32) = A.row * xb + add1[row] + add2[row]
__global__ __launch_bounds__(256) void spmm_wave(
    const int* __restrict__ row_beg, const int* __restrict__ row_end,
    const int2* __restrict__ edges, const ushort4* __restrict__ xb,
    ushort4* __restrict__ h_bf, float4* __restrict__ out,
    const ushort4* __restrict__ add1, const ushort4* __restrict__ add2,
    int final_mode) {
  int t = threadIdx.x;
  int lane = t & 63;
  int q  = lane >> 4;
  int ql = lane & 15;
  int row = blockIdx.x * 4 + (t >> 6);
  if (row >= N_NODES) return;
  int e0 = row_beg[row];
  int e1 = row_end[row];
  int len = e1 - e0;
  int nfull = len >> 4;
  float4 a = make_float4(0.f, 0.f, 0.f, 0.f);
  int e = e0 + q * 4;
  for (int it = 0; it < nfull; ++it, e += 16) {
    int2 d0 = edges[e];
    int2 d1 = edges[e + 1];
    int2 d2 = edges[e + 2];
    int2 d3 = edges[e + 3];
    ushort4 u0 = xb[(size_t)d0.x * 16 + ql];
    ushort4 u1 = xb[(size_t)d1.x * 16 + ql];
    ushort4 u2 = xb[(size_t)d2.x * 16 + ql];
    ushort4 u3 = xb[(size_t)d3.x * 16 + ql];
    float v0 = __int_as_float(d0.y), v1 = __int_as_float(d1.y);
    float v2 = __int_as_float(d2.y), v3 = __int_as_float(d3.y);
    a.x += v0 * bf2f(u0.x) + v1 * bf2f(u1.x) + v2 * bf2f(u2.x) + v3 * bf2f(u3.x);
    a.y += v0 * bf2f(u0.y) + v1 * bf2f(u1.y) + v2 * bf2f(u2.y) + v3 * bf2f(u3.y);
    a.z += v0 * bf2f(u0.z) + v1 * bf2f(u1.z) + v2 * bf2f(u2.z) + v3 * bf2f(u3.z);
    a.w += v0 * bf2f(u0.w) + v1 * bf2f(u1.w) + v2 * bf2f(u2.w) + v3 * bf2f(u3.w);
  }
  for (int ee = e0 + (nfull << 4) + q; ee < e1; ee += 4) {
    int2 d = edges[ee];
    float v = __int_as_float(d.y);
    ushort4 u = xb[(size_t)d.x * 16 + ql];
    a.x += v * bf2f(u.x); a.y += v * bf2f(u.y);
    a.z += v * bf2f(u.z); a.w += v * bf2f(u.w);
  }
#pragma unroll
  for (int m = 16; m < 64; m <<= 1) {
    a.x += __shfl_xor(a.x, m, 64);
    a.y += __shfl_xor(a.y, m, 64);
    a.z += __shfl_xor(a.z, m, 64);
    a.w += __shfl_xor(a.w, m, 64);
  }
  if (q == 0) {
    size_t oi = (size_t)row * 16 + ql;
    if (final_mode) {
      ushort4 r1 = add1[oi];
      ushort4 r2 = add2[oi];
      float4 o;
      o.x = a.x + bf2f(r1.x) + bf2f(r2.x);
      o.y = a.y + bf2f(r1.y) + bf2f(r2.y);
      o.z = a.z + bf2f(r1.z) + bf2f(r2.z);
      o.w = a.w + bf2f(r1.w) + bf2f(r2.w);
      out[oi] = o;
    } else {
      ushort4 o;
      o.x = f2bf(a.x); o.y = f2bf(a.y); o.z = f2bf(a.z); o.w = f2bf(a.w);
      h_bf[oi] = o;
    }
  }
}

extern "C" void kernel_launch(void* const* d_in, const int* in_sizes, int n_in,
                              void* d_out, int out_size, void* d_ws, size_t ws_size,
                              hipStream_t stream) {
  const float* x     = (const float*)d_in[0];
  const int*   erow  = (const int*)d_in[1];
  const int*   ecol  = (const int*)d_in[2];
  const float* evals = (const float*)d_in[3];
  float* out = (float*)d_out;

  const size_t hb_bytes   = (size_t)N_NODES * D_FEAT * 2;     // 12.8 MB (bf16)
  const size_t ecap_bytes = (size_t)NBK * CAP * sizeof(int2); // 14.41 MB
  char* ws = (char*)d_ws;
  ushort4* xbf  = (ushort4*)(ws);                        // 12.8 MB, live whole launch
  ushort4* bufA = (ushort4*)(ws + hb_bytes);             // h1 (bf16)
  int2*    tmp  = (int2*)   (ws + hb_bytes);             // aliases bufA (build only)
  ushort4* bufB = (ushort4*)(ws + 2 * hb_bytes);         // h2 (bf16)
  int*     offs = (int*)    (ws + 2 * hb_bytes);         // aliases bufB (build only)
  int2* edges   = (int2*)(ws + 3 * hb_bytes);
  int* row_beg  = (int*) (ws + 3 * hb_bytes + ecap_bytes);
  int* row_end  = (int*) (ws + 3 * hb_bytes + ecap_bytes + 400000);

  const int cblocks = (N_NODES * D_FEAT / 4 + 255) / 256;  // 6250
  const int sblocks = N_NODES / 4;                         // 25000

  // ---- convert + build bucket-CSR ----
  convert_x<<<cblocks, 256, 0, stream>>>((const float4*)x, xbf);
  bin_edges<<<KBLK, 1024, 0, stream>>>(erow, ecol, evals, tmp, offs);
  build_csr<<<NBK, 256, 0, stream>>>(tmp, offs, edges, row_beg, row_end);

  // L1: bufA = bf16(A xbf)      (tmp dead after build)
  spmm_wave<<<sblocks, 256, 0, stream>>>(row_beg, row_end, edges, xbf,
                                         bufA, nullptr, nullptr, nullptr, 0);
  // L2: bufB = bf16(A bufA)     (offs dead)
  spmm_wave<<<sblocks, 256, 0, stream>>>(row_beg, row_end, edges, bufA,
                                         bufB, nullptr, nullptr, nullptr, 0);
  // L3: out = A bufB + bufA + bufB   (f32 output)
  spmm_wave<<<sblocks, 256, 0, stream>>>(row_beg, row_end, edges, bufB,
                                         nullptr, (float4*)out, bufA, bufB, 1);
}

// Round 7
// 272.795 us; speedup vs baseline: 1.3377x; 1.3377x over previous
//
#include <hip/hip_runtime.h>

#define N_NODES 100000
#define N_EDGES 1600000
#define D_FEAT  64

#define RSHIFT 8
#define RPB    256                              // rows per bucket
#define NBK    ((N_NODES + RPB - 1) / RPB)      // 391 row-buckets
#define CAP    4608                             // bucket edge capacity
#define EPB    4096                             // edges per bin block
#define KBLK   ((N_EDGES + EPB - 1) / EPB)      // 391 bin blocks
#define OROW   (NBK + 1)
#define CMAX   ((CAP + 255) / 256)              // 18 cached edges/thread

__device__ __forceinline__ float bf2f(unsigned short u) {
  union { unsigned int i; float f; } v; v.i = ((unsigned int)u) << 16; return v.f;
}
__device__ __forceinline__ unsigned short f2bf(float f) {
  union { float f; unsigned int i; } v; v.f = f;
  unsigned int b = v.i;
  return (unsigned short)((b + 0x7FFFu + ((b >> 16) & 1u)) >> 16);  // RNE
}

// ---- x (f32) -> bf16 once; all 3 layers gather 128B rows (1 line/edge) ----
__global__ __launch_bounds__(256) void convert_x(
    const float4* __restrict__ xin, ushort4* __restrict__ xout) {
  int i = blockIdx.x * 256 + threadIdx.x;
  if (i < (N_NODES * D_FEAT / 4)) {
    float4 v = xin[i];
    ushort4 o;
    o.x = f2bf(v.x); o.y = f2bf(v.y); o.z = f2bf(v.z); o.w = f2bf(v.w);
    xout[i] = o;
  }
}

// ---- pass 1: block-local counting sort of 4096 edges by bucket ----
__global__ __launch_bounds__(1024) void bin_edges(
    const int* __restrict__ erow, const int* __restrict__ ecol,
    const float* __restrict__ evals, int2* __restrict__ tmp,
    int* __restrict__ offs) {
  __shared__ int hist[NBK];
  __shared__ int sc[NBK];
  int t = threadIdx.x;
  int k = blockIdx.x;
  if (t < NBK) hist[t] = 0;
  __syncthreads();
  int base = k * EPB;
  int nk = N_EDGES - base; if (nk > EPB) nk = EPB;
  int key[4], vb[4], rk[4], bk[4];
#pragma unroll
  for (int j = 0; j < 4; ++j) {
    int li = j * 1024 + t;
    bk[j] = -1;
    if (li < nk) {
      int e = base + li;
      int r = erow[e];
      key[j] = ((r & (RPB - 1)) << 17) | ecol[e];
      vb[j]  = __float_as_int(evals[e]);
      bk[j]  = r >> RSHIFT;
      rk[j]  = atomicAdd(&hist[bk[j]], 1);
    }
  }
  __syncthreads();
  if (t < NBK) sc[t] = hist[t];
  __syncthreads();
  for (int off = 1; off < NBK; off <<= 1) {
    int u = (t >= off && t < NBK) ? sc[t - off] : 0;
    __syncthreads();
    if (t < NBK) sc[t] += u;
    __syncthreads();
  }
  if (t < NBK) {
    int ex = sc[t] - hist[t];
    sc[t] = ex;
    offs[k * OROW + t] = ex;
  }
  if (t == 0) offs[k * OROW + NBK] = nk;
  __syncthreads();
#pragma unroll
  for (int j = 0; j < 4; ++j) {
    if (bk[j] >= 0) {
      int pos = sc[bk[j]] + rk[j];
      tmp[k * EPB + pos] = make_int2(key[j], vb[j]);
    }
  }
}

// ---- pass 2: load-balanced flat gather. Block b builds a prefix (roff) over
// its 391 run lengths, then a flat i-loop binary-searches the owning run:
// all 256 lanes stay active, consecutive i read consecutive addresses.
__global__ __launch_bounds__(256) void build_csr(
    const int2* __restrict__ tmp, const int* __restrict__ offs,
    int2* __restrict__ edges, int* __restrict__ row_beg,
    int* __restrict__ row_end) {
  __shared__ int roff[2 * 256 + 1];
  __shared__ int rbase[2 * 256];
  __shared__ int ssum[256];
  __shared__ int hist[RPB];
  __shared__ int cur[RPB];
  int b = blockIdx.x;
  int t = threadIdx.x;
  // two runs per thread: k = 2t, 2t+1 (k-order preserved)
  int k0 = 2 * t, k1 = 2 * t + 1;
  int l0 = 0, l1 = 0, s0 = 0, s1 = 0;
  if (k0 < KBLK) { s0 = offs[k0 * OROW + b]; l0 = offs[k0 * OROW + b + 1] - s0; }
  if (k1 < KBLK) { s1 = offs[k1 * OROW + b]; l1 = offs[k1 * OROW + b + 1] - s1; }
  ssum[t] = l0 + l1;
  hist[t] = 0;
  __syncthreads();
  for (int off = 1; off < 256; off <<= 1) {
    int u = (t >= off) ? ssum[t - off] : 0;
    __syncthreads();
    ssum[t] += u;
    __syncthreads();
  }
  int rex0 = ssum[t] - (l0 + l1);
  if (k0 < KBLK) { roff[k0] = rex0;      rbase[k0] = s0; }
  if (k1 < KBLK) { roff[k1] = rex0 + l0; rbase[k1] = s1; }
  if (t == 255) roff[KBLK] = ssum[255];
  __syncthreads();
  int cnt = roff[KBLK];
  if (cnt > CAP) cnt = CAP;
  // pass A: flat gather + register cache + row histogram
  int2 cache[CMAX];
  int nc = 0;
  for (int i = t; i < cnt; i += 256) {
    int lo = 0, hi = KBLK;                    // roff[lo] <= i < roff[hi]
    while (hi - lo > 1) {
      int mid = (lo + hi) >> 1;
      if (roff[mid] <= i) lo = mid; else hi = mid;
    }
    int2 ed = tmp[lo * EPB + rbase[lo] + (i - roff[lo])];
    cache[nc++] = ed;
    atomicAdd(&hist[ed.x >> 17], 1);
  }
  __syncthreads();
  int v = hist[t];
  cur[t] = v;
  __syncthreads();
  for (int off = 1; off < 256; off <<= 1) {
    int u = (t >= off) ? cur[t - off] : 0;
    __syncthreads();
    cur[t] += u;
    __syncthreads();
  }
  int excl = cur[t] - v;
  int base = b * CAP;
  int gr = b * RPB + t;
  if (gr < N_NODES) {
    row_beg[gr] = base + excl;
    row_end[gr] = base + excl + v;
  }
  __syncthreads();
  cur[t] = excl;
  __syncthreads();
  // pass B: scatter from register cache into L2-resident 36KB window
  nc = 0;
  for (int i = t; i < cnt; i += 256) {
    int2 ed = cache[nc++];
    int pos = atomicAdd(&cur[ed.x >> 17], 1);
    edges[base + pos] = make_int2(ed.x & 0x1FFFF, ed.y);
  }
}

// ---- SpMM: one row/wave, 4 edges/iter per quarter, bf16 gather, f32 acc ----
__global__ __launch_bounds__(256) void spmm_wave(
    const int* __restrict__ row_beg, const int* __restrict__ row_end,
    const int2* __restrict__ edges, const ushort4* __restrict__ xb,
    ushort4* __restrict__ h_bf, float4* __restrict__ out,
    const ushort4* __restrict__ add1, const ushort4* __restrict__ add2,
    int final_mode) {
  int t = threadIdx.x;
  int lane = t & 63;
  int q  = lane >> 4;
  int ql = lane & 15;
  int row = blockIdx.x * 4 + (t >> 6);
  if (row >= N_NODES) return;
  int e0 = row_beg[row];
  int e1 = row_end[row];
  int len = e1 - e0;
  int nfull = len >> 4;
  float4 a = make_float4(0.f, 0.f, 0.f, 0.f);
  int e = e0 + q * 4;
  for (int it = 0; it < nfull; ++it, e += 16) {
    int2 d0 = edges[e];
    int2 d1 = edges[e + 1];
    int2 d2 = edges[e + 2];
    int2 d3 = edges[e + 3];
    ushort4 u0 = xb[(size_t)d0.x * 16 + ql];
    ushort4 u1 = xb[(size_t)d1.x * 16 + ql];
    ushort4 u2 = xb[(size_t)d2.x * 16 + ql];
    ushort4 u3 = xb[(size_t)d3.x * 16 + ql];
    float v0 = __int_as_float(d0.y), v1 = __int_as_float(d1.y);
    float v2 = __int_as_float(d2.y), v3 = __int_as_float(d3.y);
    a.x += v0 * bf2f(u0.x) + v1 * bf2f(u1.x) + v2 * bf2f(u2.x) + v3 * bf2f(u3.x);
    a.y += v0 * bf2f(u0.y) + v1 * bf2f(u1.y) + v2 * bf2f(u2.y) + v3 * bf2f(u3.y);
    a.z += v0 * bf2f(u0.z) + v1 * bf2f(u1.z) + v2 * bf2f(u2.z) + v3 * bf2f(u3.z);
    a.w += v0 * bf2f(u0.w) + v1 * bf2f(u1.w) + v2 * bf2f(u2.w) + v3 * bf2f(u3.w);
  }
  for (int ee = e0 + (nfull << 4) + q; ee < e1; ee += 4) {
    int2 d = edges[ee];
    float v = __int_as_float(d.y);
    ushort4 u = xb[(size_t)d.x * 16 + ql];
    a.x += v * bf2f(u.x); a.y += v * bf2f(u.y);
    a.z += v * bf2f(u.z); a.w += v * bf2f(u.w);
  }
#pragma unroll
  for (int m = 16; m < 64; m <<= 1) {
    a.x += __shfl_xor(a.x, m, 64);
    a.y += __shfl_xor(a.y, m, 64);
    a.z += __shfl_xor(a.z, m, 64);
    a.w += __shfl_xor(a.w, m, 64);
  }
  if (q == 0) {
    size_t oi = (size_t)row * 16 + ql;
    if (final_mode) {
      ushort4 r1 = add1[oi];
      ushort4 r2 = add2[oi];
      float4 o;
      o.x = a.x + bf2f(r1.x) + bf2f(r2.x);
      o.y = a.y + bf2f(r1.y) + bf2f(r2.y);
      o.z = a.z + bf2f(r1.z) + bf2f(r2.z);
      o.w = a.w + bf2f(r1.w) + bf2f(r2.w);
      out[oi] = o;
    } else {
      ushort4 o;
      o.x = f2bf(a.x); o.y = f2bf(a.y); o.z = f2bf(a.z); o.w = f2bf(a.w);
      h_bf[oi] = o;
    }
  }
}

extern "C" void kernel_launch(void* const* d_in, const int* in_sizes, int n_in,
                              void* d_out, int out_size, void* d_ws, size_t ws_size,
                              hipStream_t stream) {
  const float* x     = (const float*)d_in[0];
  const int*   erow  = (const int*)d_in[1];
  const int*   ecol  = (const int*)d_in[2];
  const float* evals = (const float*)d_in[3];
  float* out = (float*)d_out;

  const size_t hb_bytes   = (size_t)N_NODES * D_FEAT * 2;     // 12.8 MB (bf16)
  const size_t ecap_bytes = (size_t)NBK * CAP * sizeof(int2); // 14.41 MB
  char* ws = (char*)d_ws;
  ushort4* xbf  = (ushort4*)(ws);                        // 12.8 MB, live whole launch
  ushort4* bufA = (ushort4*)(ws + hb_bytes);             // h1 (bf16)
  int2*    tmp  = (int2*)   (ws + hb_bytes);             // aliases bufA (build only)
  ushort4* bufB = (ushort4*)(ws + 2 * hb_bytes);         // h2 (bf16)
  int*     offs = (int*)    (ws + 2 * hb_bytes);         // aliases bufB (build only)
  int2* edges   = (int2*)(ws + 3 * hb_bytes);
  int* row_beg  = (int*) (ws + 3 * hb_bytes + ecap_bytes);
  int* row_end  = (int*) (ws + 3 * hb_bytes + ecap_bytes + 400000);

  const int cblocks = (N_NODES * D_FEAT / 4 + 255) / 256;  // 6250
  const int sblocks = N_NODES / 4;                         // 25000

  convert_x<<<cblocks, 256, 0, stream>>>((const float4*)x, xbf);
  bin_edges<<<KBLK, 1024, 0, stream>>>(erow, ecol, evals, tmp, offs);
  build_csr<<<NBK, 256, 0, stream>>>(tmp, offs, edges, row_beg, row_end);

  // L1: bufA = bf16(A xbf)      (tmp dead after build)
  spmm_wave<<<sblocks, 256, 0, stream>>>(row_beg, row_end, edges, xbf,
                                         bufA, nullptr, nullptr, nullptr, 0);
  // L2: bufB = bf16(A bufA)     (offs dead)
  spmm_wave<<<sblocks, 256, 0, stream>>>(row_beg, row_end, edges, bufA,
                                         bufB, nullptr, nullptr, nullptr, 0);
  // L3: out = A bufB + bufA + bufB   (f32 output)
  spmm_wave<<<sblocks, 256, 0, stream>>>(row_beg, row_end, edges, bufB,
                                         nullptr, (float4*)out, bufA, bufB, 1);
}

// Round 9
// 250.045 us; speedup vs baseline: 1.4594x; 1.0910x over previous
//
#include <hip/hip_runtime.h>

#define N_NODES 100000
#define N_EDGES 1600000
#define D_FEAT  64

#define RSHIFT 8
#define RPB    256                              // rows per bucket
#define NBK    ((N_NODES + RPB - 1) / RPB)      // 391 row-buckets
#define CAP    5120                             // bucket edge capacity (even; 16B-aligned base)
#define EPB    4096                             // edges per bin block
#define KBLK   ((N_EDGES + EPB - 1) / EPB)      // 391 bin blocks
#define OROW   (NBK + 1)

__device__ __forceinline__ float bf2f(unsigned short u) {
  union { unsigned int i; float f; } v; v.i = ((unsigned int)u) << 16; return v.f;
}
__device__ __forceinline__ unsigned short f2bf(float f) {
  union { float f; unsigned int i; } v; v.f = f;
  unsigned int b = v.i;
  return (unsigned short)((b + 0x7FFFu + ((b >> 16) & 1u)) >> 16);  // RNE
}
// bf16 pair unpack from one int (elem0 = low half)
__device__ __forceinline__ float ulo(int u) { return __int_as_float(u << 16); }
__device__ __forceinline__ float uhi(int u) { return __int_as_float(u & 0xFFFF0000); }
__device__ __forceinline__ int pk(float a, float b) {
  return (int)f2bf(a) | ((int)f2bf(b) << 16);
}

// ---- x (f32) -> bf16 once; rows become 128B = 1 cache line ----
__global__ __launch_bounds__(256) void convert_x(
    const float4* __restrict__ xin, ushort4* __restrict__ xout) {
  int i = blockIdx.x * 256 + threadIdx.x;
  if (i < (N_NODES * D_FEAT / 4)) {
    float4 v = xin[i];
    ushort4 o;
    o.x = f2bf(v.x); o.y = f2bf(v.y); o.z = f2bf(v.z); o.w = f2bf(v.w);
    xout[i] = o;
  }
}

// ---- pass 1: block-local counting sort of 4096 edges by bucket ----
__global__ __launch_bounds__(1024) void bin_edges(
    const int* __restrict__ erow, const int* __restrict__ ecol,
    const float* __restrict__ evals, int2* __restrict__ tmp,
    int* __restrict__ offs) {
  __shared__ int hist[NBK];
  __shared__ int sc[NBK];
  int t = threadIdx.x;
  int k = blockIdx.x;
  if (t < NBK) hist[t] = 0;
  __syncthreads();
  int base = k * EPB;
  int nk = N_EDGES - base; if (nk > EPB) nk = EPB;
  int key[4], vb[4], rk[4], bk[4];
#pragma unroll
  for (int j = 0; j < 4; ++j) {
    int li = j * 1024 + t;
    bk[j] = -1;
    if (li < nk) {
      int e = base + li;
      int r = erow[e];
      key[j] = ((r & (RPB - 1)) << 17) | ecol[e];
      vb[j]  = __float_as_int(evals[e]);
      bk[j]  = r >> RSHIFT;
      rk[j]  = atomicAdd(&hist[bk[j]], 1);
    }
  }
  __syncthreads();
  if (t < NBK) sc[t] = hist[t];
  __syncthreads();
  for (int off = 1; off < NBK; off <<= 1) {
    int u = (t >= off && t < NBK) ? sc[t - off] : 0;
    __syncthreads();
    if (t < NBK) sc[t] += u;
    __syncthreads();
  }
  if (t < NBK) {
    int ex = sc[t] - hist[t];
    sc[t] = ex;
    offs[k * OROW + t] = ex;
  }
  if (t == 0) offs[k * OROW + NBK] = nk;
  __syncthreads();
#pragma unroll
  for (int j = 0; j < 4; ++j) {
    if (bk[j] >= 0) {
      int pos = sc[bk[j]] + rk[j];
      tmp[k * EPB + pos] = make_int2(key[j], vb[j]);
    }
  }
}

// ---- pass 2: octet-per-run sweep. Rows padded to EVEN edge counts so every
// row starts 16B-aligned in the edge array (pad edge = {0,0} adds nothing).
__global__ __launch_bounds__(256) void build_csr(
    const int2* __restrict__ tmp, const int* __restrict__ offs,
    int2* __restrict__ edges, int* __restrict__ row_beg,
    int* __restrict__ row_end) {
  __shared__ int hist[RPB];
  __shared__ int cur[RPB];
  int b = blockIdx.x;
  int t = threadIdx.x;
  int oct = t >> 3;        // 32 octets per block
  int ol  = t & 7;
  hist[t] = 0;
  __syncthreads();
  // pass A: histogram of local rows (octet-swept runs)
  for (int k = oct; k < KBLK; k += 32) {
    int o0 = offs[k * OROW + b];
    int o1 = offs[k * OROW + b + 1];
    const int2* seg = tmp + k * EPB;
    for (int i = o0 + ol; i < o1; i += 8)
      atomicAdd(&hist[seg[i].x >> 17], 1);
  }
  __syncthreads();
  int v  = hist[t];
  int v2 = (v + 1) & ~1;   // even-padded length
  cur[t] = v2;
  __syncthreads();
  for (int off = 1; off < 256; off <<= 1) {
    int u = (t >= off) ? cur[t - off] : 0;
    __syncthreads();
    cur[t] += u;
    __syncthreads();
  }
  int excl2 = cur[t] - v2;
  int base = b * CAP;
  int gr = b * RPB + t;
  if (gr < N_NODES) {
    row_beg[gr] = base + excl2;
    row_end[gr] = base + excl2 + v;
  }
  if (v & 1) edges[base + excl2 + v] = make_int2(0, 0);  // zero pad slot
  __syncthreads();
  cur[t] = excl2;
  __syncthreads();
  // pass B: scatter into L2-resident 40KB bucket window
  for (int k = oct; k < KBLK; k += 32) {
    int o0 = offs[k * OROW + b];
    int o1 = offs[k * OROW + b + 1];
    const int2* seg = tmp + k * EPB;
    for (int i = o0 + ol; i < o1; i += 8) {
      int2 ed = seg[i];
      int pos = atomicAdd(&cur[ed.x >> 17], 1);
      edges[base + pos] = make_int2(ed.x & 0x1FFFF, ed.y);
    }
  }
}

// ---- SpMM: one row/wave, OCTET layout: 8 lanes/edge, int4 (16B) gathers.
// Per 16-edge window per lane: 1 int4 edge load (2 edges) + 2 int4 x-gathers.
__global__ __launch_bounds__(256) void spmm_wave(
    const int* __restrict__ row_beg, const int* __restrict__ row_end,
    const int2* __restrict__ edges, const int4* __restrict__ xq,
    int4* __restrict__ h_q, float4* __restrict__ out,
    const int4* __restrict__ add1, const int4* __restrict__ add2,
    int final_mode) {
  int t = threadIdx.x;
  int lane = t & 63;
  int oct = lane >> 3;     // 0..7: which edge pair
  int ol  = lane & 7;      // 0..7: which 16B of the 128B row
  int row = blockIdx.x * 4 + (t >> 6);
  int e0 = row_beg[row];
  int e1 = row_end[row];
  int len = e1 - e0;       // e0 even; rows padded so int4 loads are aligned
  float a[8];
#pragma unroll
  for (int j = 0; j < 8; ++j) a[j] = 0.f;
  int nfull = len >> 4;
  int e = e0;
  for (int it = 0; it < nfull; ++it, e += 16) {
    const int4* ep = (const int4*)(edges + e);
    int4 m = ep[oct];                       // edges e+2*oct, e+2*oct+1
    int4 g0 = xq[(size_t)m.x * 8 + ol];
    int4 g1 = xq[(size_t)m.z * 8 + ol];
    float v0 = __int_as_float(m.y);
    float v1 = __int_as_float(m.w);
    a[0] += v0 * ulo(g0.x) + v1 * ulo(g1.x);
    a[1] += v0 * uhi(g0.x) + v1 * uhi(g1.x);
    a[2] += v0 * ulo(g0.y) + v1 * ulo(g1.y);
    a[3] += v0 * uhi(g0.y) + v1 * uhi(g1.y);
    a[4] += v0 * ulo(g0.z) + v1 * ulo(g1.z);
    a[5] += v0 * uhi(g0.z) + v1 * uhi(g1.z);
    a[6] += v0 * ulo(g0.w) + v1 * ulo(g1.w);
    a[7] += v0 * uhi(g0.w) + v1 * uhi(g1.w);
  }
  // Remainder: round UP to include the (real, pad) pair for odd lengths —
  // the pad edge {col=0, val=0} contributes exactly 0. (R7 bug: >>1 floored
  // away the last real edge of every odd-length row.)
  int pairs = (e1 - e + 1) >> 1;            // 0..8 remaining pairs
  if (oct < pairs) {
    const int4* ep = (const int4*)(edges + e);
    int4 m = ep[oct];
    int4 g0 = xq[(size_t)m.x * 8 + ol];
    int4 g1 = xq[(size_t)m.z * 8 + ol];
    float v0 = __int_as_float(m.y);
    float v1 = __int_as_float(m.w);
    a[0] += v0 * ulo(g0.x) + v1 * ulo(g1.x);
    a[1] += v0 * uhi(g0.x) + v1 * uhi(g1.x);
    a[2] += v0 * ulo(g0.y) + v1 * ulo(g1.y);
    a[3] += v0 * uhi(g0.y) + v1 * uhi(g1.y);
    a[4] += v0 * ulo(g0.z) + v1 * ulo(g1.z);
    a[5] += v0 * uhi(g0.z) + v1 * uhi(g1.z);
    a[6] += v0 * ulo(g0.w) + v1 * ulo(g1.w);
    a[7] += v0 * uhi(g0.w) + v1 * uhi(g1.w);
  }
  // reduce across the 8 octets (same ol keeps the same 16B slice)
#pragma unroll
  for (int m = 8; m < 64; m <<= 1) {
#pragma unroll
    for (int j = 0; j < 8; ++j) a[j] += __shfl_xor(a[j], m, 64);
  }
  if (oct == 0) {
    size_t oi = (size_t)row * 8 + ol;
    if (final_mode) {
      int4 r1 = add1[oi];
      int4 r2 = add2[oi];
      float4 lo, hi;
      lo.x = a[0] + ulo(r1.x) + ulo(r2.x);
      lo.y = a[1] + uhi(r1.x) + uhi(r2.x);
      lo.z = a[2] + ulo(r1.y) + ulo(r2.y);
      lo.w = a[3] + uhi(r1.y) + uhi(r2.y);
      hi.x = a[4] + ulo(r1.z) + ulo(r2.z);
      hi.y = a[5] + uhi(r1.z) + uhi(r2.z);
      hi.z = a[6] + ulo(r1.w) + ulo(r2.w);
      hi.w = a[7] + uhi(r1.w) + uhi(r2.w);
      out[(size_t)row * 16 + ol * 2]     = lo;
      out[(size_t)row * 16 + ol * 2 + 1] = hi;
    } else {
      int4 p;
      p.x = pk(a[0], a[1]);
      p.y = pk(a[2], a[3]);
      p.z = pk(a[4], a[5]);
      p.w = pk(a[6], a[7]);
      h_q[oi] = p;
    }
  }
}

extern "C" void kernel_launch(void* const* d_in, const int* in_sizes, int n_in,
                              void* d_out, int out_size, void* d_ws, size_t ws_size,
                              hipStream_t stream) {
  const float* x     = (const float*)d_in[0];
  const int*   erow  = (const int*)d_in[1];
  const int*   ecol  = (const int*)d_in[2];
  const float* evals = (const float*)d_in[3];
  float* out = (float*)d_out;

  const size_t hb_bytes   = (size_t)N_NODES * D_FEAT * 2;     // 12.8 MB (bf16)
  const size_t ecap_bytes = (size_t)NBK * CAP * sizeof(int2); // 16.0 MB
  char* ws = (char*)d_ws;
  int4*    xbf  = (int4*)   (ws);                        // 12.8 MB, live whole launch
  int4*    bufA = (int4*)   (ws + hb_bytes);             // h1 (bf16)
  int2*    tmp  = (int2*)   (ws + hb_bytes);             // aliases bufA (build only)
  int4*    bufB = (int4*)   (ws + 2 * hb_bytes);         // h2 (bf16)
  int*     offs = (int*)    (ws + 2 * hb_bytes);         // aliases bufB (build only)
  int2* edges   = (int2*)(ws + 3 * hb_bytes);
  int* row_beg  = (int*) (ws + 3 * hb_bytes + ecap_bytes);
  int* row_end  = (int*) (ws + 3 * hb_bytes + ecap_bytes + 400000);

  const int cblocks = (N_NODES * D_FEAT / 4 + 255) / 256;  // 6250
  const int sblocks = N_NODES / 4;                         // 25000

  convert_x<<<cblocks, 256, 0, stream>>>((const float4*)x, (ushort4*)xbf);
  bin_edges<<<KBLK, 1024, 0, stream>>>(erow, ecol, evals, tmp, offs);
  build_csr<<<NBK, 256, 0, stream>>>(tmp, offs, edges, row_beg, row_end);

  // L1: bufA = bf16(A xbf)      (tmp dead after build)
  spmm_wave<<<sblocks, 256, 0, stream>>>(row_beg, row_end, edges, xbf,
                                         bufA, nullptr, nullptr, nullptr, 0);
  // L2: bufB = bf16(A bufA)     (offs dead)
  spmm_wave<<<sblocks, 256, 0, stream>>>(row_beg, row_end, edges, bufA,
                                         bufB, nullptr, nullptr, nullptr, 0);
  // L3: out = A bufB + bufA + bufB   (f32 output)
  spmm_wave<<<sblocks, 256, 0, stream>>>(row_beg, row_end, edges, bufB,
                                         nullptr, (float4*)out, bufA, bufB, 1);
}

// Round 10
// 244.706 us; speedup vs baseline: 1.4913x; 1.0218x over previous
//
#include <hip/hip_runtime.h>

#define N_NODES 100000
#define N_EDGES 1600000
#define D_FEAT  64

#define RSHIFT 8
#define RPB    256                              // rows per bucket
#define NBK    ((N_NODES + RPB - 1) / RPB)      // 391 row-buckets
#define CAP    5120                             // bucket edge capacity (even; 16B-aligned base)
#define EPB    4096                             // edges per bin block
#define KBLK   ((N_EDGES + EPB - 1) / EPB)      // 391 bin blocks
#define OROW   (NBK + 1)
#define CVB    ((N_NODES * D_FEAT / 4 + 1023) / 1024)  // 1563 convert blocks

typedef float f32x2 __attribute__((ext_vector_type(2)));

__device__ __forceinline__ unsigned short f2bf(float f) {
  union { float f; unsigned int i; } v; v.f = f;
  unsigned int b = v.i;
  return (unsigned short)((b + 0x7FFFu + ((b >> 16) & 1u)) >> 16);  // RNE
}
__device__ __forceinline__ float ulo(int u) { return __int_as_float(u << 16); }
__device__ __forceinline__ float uhi(int u) { return __int_as_float(u & 0xFFFF0000); }
__device__ __forceinline__ f32x2 upk(int u) {  // {elem0, elem1} of a bf16 pair
  f32x2 r; r.x = ulo(u); r.y = uhi(u); return r;
}
__device__ __forceinline__ int pk(float a, float b) {
  return (int)f2bf(a) | ((int)f2bf(b) << 16);
}

// ---- fused: blocks [0,KBLK) bin edges; blocks [KBLK, KBLK+CVB) convert x ----
__global__ __launch_bounds__(1024) void convert_bin(
    const float4* __restrict__ xin, ushort4* __restrict__ xout,
    const int* __restrict__ erow, const int* __restrict__ ecol,
    const float* __restrict__ evals, int2* __restrict__ tmp,
    int* __restrict__ offs) {
  __shared__ int hist[NBK];
  __shared__ int sc[NBK];
  int t = threadIdx.x;
  int k = blockIdx.x;
  if (k >= KBLK) {                       // ---- convert path ----
    int i = (k - KBLK) * 1024 + t;
    if (i < N_NODES * D_FEAT / 4) {
      float4 v = xin[i];
      ushort4 o;
      o.x = f2bf(v.x); o.y = f2bf(v.y); o.z = f2bf(v.z); o.w = f2bf(v.w);
      xout[i] = o;
    }
    return;
  }
  // ---- bin path: block-local counting sort of 4096 edges by bucket ----
  if (t < NBK) hist[t] = 0;
  __syncthreads();
  int base = k * EPB;
  int nk = N_EDGES - base; if (nk > EPB) nk = EPB;
  int key[4], vb[4], rk[4], bk[4];
#pragma unroll
  for (int j = 0; j < 4; ++j) {
    int li = j * 1024 + t;
    bk[j] = -1;
    if (li < nk) {
      int e = base + li;
      int r = erow[e];
      key[j] = ((r & (RPB - 1)) << 17) | ecol[e];
      vb[j]  = __float_as_int(evals[e]);
      bk[j]  = r >> RSHIFT;
      rk[j]  = atomicAdd(&hist[bk[j]], 1);
    }
  }
  __syncthreads();
  if (t < NBK) sc[t] = hist[t];
  __syncthreads();
  for (int off = 1; off < NBK; off <<= 1) {
    int u = (t >= off && t < NBK) ? sc[t - off] : 0;
    __syncthreads();
    if (t < NBK) sc[t] += u;
    __syncthreads();
  }
  if (t < NBK) {
    int ex = sc[t] - hist[t];
    sc[t] = ex;
    offs[k * OROW + t] = ex;
  }
  if (t == 0) offs[k * OROW + NBK] = nk;
  __syncthreads();
#pragma unroll
  for (int j = 0; j < 4; ++j) {
    if (bk[j] >= 0) {
      int pos = sc[bk[j]] + rk[j];
      tmp[k * EPB + pos] = make_int2(key[j], vb[j]);
    }
  }
}

// ---- pass 2: octet-per-run sweep. Rows padded to EVEN edge counts so every
// row starts 16B-aligned in the edge array (pad edge = {0,0} adds nothing).
__global__ __launch_bounds__(256) void build_csr(
    const int2* __restrict__ tmp, const int* __restrict__ offs,
    int2* __restrict__ edges, int* __restrict__ row_beg,
    int* __restrict__ row_end) {
  __shared__ int hist[RPB];
  __shared__ int cur[RPB];
  int b = blockIdx.x;
  int t = threadIdx.x;
  int oct = t >> 3;        // 32 octets per block
  int ol  = t & 7;
  hist[t] = 0;
  __syncthreads();
  for (int k = oct; k < KBLK; k += 32) {
    int o0 = offs[k * OROW + b];
    int o1 = offs[k * OROW + b + 1];
    const int2* seg = tmp + k * EPB;
    for (int i = o0 + ol; i < o1; i += 8)
      atomicAdd(&hist[seg[i].x >> 17], 1);
  }
  __syncthreads();
  int v  = hist[t];
  int v2 = (v + 1) & ~1;   // even-padded length
  cur[t] = v2;
  __syncthreads();
  for (int off = 1; off < 256; off <<= 1) {
    int u = (t >= off) ? cur[t - off] : 0;
    __syncthreads();
    cur[t] += u;
    __syncthreads();
  }
  int excl2 = cur[t] - v2;
  int base = b * CAP;
  int gr = b * RPB + t;
  if (gr < N_NODES) {
    row_beg[gr] = base + excl2;
    row_end[gr] = base + excl2 + v;
  }
  if (v & 1) edges[base + excl2 + v] = make_int2(0, 0);  // zero pad slot
  __syncthreads();
  cur[t] = excl2;
  __syncthreads();
  for (int k = oct; k < KBLK; k += 32) {
    int o0 = offs[k * OROW + b];
    int o1 = offs[k * OROW + b + 1];
    const int2* seg = tmp + k * EPB;
    for (int i = o0 + ol; i < o1; i += 8) {
      int2 ed = seg[i];
      int pos = atomicAdd(&cur[ed.x >> 17], 1);
      edges[base + pos] = make_int2(ed.x & 0x1FFFF, ed.y);
    }
  }
}

// ---- SpMM: one row/wave, octet layout, 32-edge unroll, packed f32x2 FMA ----
__global__ __launch_bounds__(256) void spmm_wave(
    const int* __restrict__ row_beg, const int* __restrict__ row_end,
    const int2* __restrict__ edges, const int4* __restrict__ xq,
    int4* __restrict__ h_q, float4* __restrict__ out,
    const int4* __restrict__ add1, const int4* __restrict__ add2,
    int final_mode) {
  int t = threadIdx.x;
  int lane = t & 63;
  int oct = lane >> 3;     // 0..7: which edge pair
  int ol  = lane & 7;      // 0..7: which 16B of the 128B row
  int row = blockIdx.x * 4 + (t >> 6);
  int e0 = row_beg[row];
  int e1 = row_end[row];
  const int4* ebase = (const int4*)edges;   // pair index = e>>1 (e always even)
  f32x2 c0 = {0.f, 0.f}, c1 = {0.f, 0.f}, c2 = {0.f, 0.f}, c3 = {0.f, 0.f};

#define WIN(p) { \
    int4 m = ebase[(p) + oct]; \
    int4 g0 = xq[(size_t)m.x * 8 + ol]; \
    int4 g1 = xq[(size_t)m.z * 8 + ol]; \
    float v0 = __int_as_float(m.y), v1 = __int_as_float(m.w); \
    f32x2 vv0 = {v0, v0}, vv1 = {v1, v1}; \
    c0 += vv0 * upk(g0.x) + vv1 * upk(g1.x); \
    c1 += vv0 * upk(g0.y) + vv1 * upk(g1.y); \
    c2 += vv0 * upk(g0.z) + vv1 * upk(g1.z); \
    c3 += vv0 * upk(g0.w) + vv1 * upk(g1.w); \
  }

  int nw = (e1 - e0) >> 4;                  // full 16-edge windows
  int e = e0;
  int it = 0;
  for (; it + 2 <= nw; it += 2, e += 32) {  // two independent windows in flight
    int p = e >> 1;
    WIN(p);
    WIN(p + 8);
  }
  if (it < nw) { WIN(e >> 1); e += 16; }
  // Remainder: round UP so odd lengths include the (real, pad) pair — the
  // pad edge {col 0, val 0} contributes exactly 0.
  int pairs = (e1 - e + 1) >> 1;            // 0..8 remaining pairs
  if (oct < pairs) { WIN(e >> 1); }
#undef WIN

  // reduce across the 8 octets (same ol keeps the same 16B slice)
#pragma unroll
  for (int m = 8; m < 64; m <<= 1) {
    c0.x += __shfl_xor(c0.x, m, 64); c0.y += __shfl_xor(c0.y, m, 64);
    c1.x += __shfl_xor(c1.x, m, 64); c1.y += __shfl_xor(c1.y, m, 64);
    c2.x += __shfl_xor(c2.x, m, 64); c2.y += __shfl_xor(c2.y, m, 64);
    c3.x += __shfl_xor(c3.x, m, 64); c3.y += __shfl_xor(c3.y, m, 64);
  }
  if (oct == 0) {
    size_t oi = (size_t)row * 8 + ol;
    if (final_mode) {
      int4 r1 = add1[oi];
      int4 r2 = add2[oi];
      float4 lo, hi;
      lo.x = c0.x + ulo(r1.x) + ulo(r2.x);
      lo.y = c0.y + uhi(r1.x) + uhi(r2.x);
      lo.z = c1.x + ulo(r1.y) + ulo(r2.y);
      lo.w = c1.y + uhi(r1.y) + uhi(r2.y);
      hi.x = c2.x + ulo(r1.z) + ulo(r2.z);
      hi.y = c2.y + uhi(r1.z) + uhi(r2.z);
      hi.z = c3.x + ulo(r1.w) + ulo(r2.w);
      hi.w = c3.y + uhi(r1.w) + uhi(r2.w);
      out[(size_t)row * 16 + ol * 2]     = lo;
      out[(size_t)row * 16 + ol * 2 + 1] = hi;
    } else {
      int4 p;
      p.x = pk(c0.x, c0.y);
      p.y = pk(c1.x, c1.y);
      p.z = pk(c2.x, c2.y);
      p.w = pk(c3.x, c3.y);
      h_q[oi] = p;
    }
  }
}

extern "C" void kernel_launch(void* const* d_in, const int* in_sizes, int n_in,
                              void* d_out, int out_size, void* d_ws, size_t ws_size,
                              hipStream_t stream) {
  const float* x     = (const float*)d_in[0];
  const int*   erow  = (const int*)d_in[1];
  const int*   ecol  = (const int*)d_in[2];
  const float* evals = (const float*)d_in[3];
  float* out = (float*)d_out;

  const size_t hb_bytes   = (size_t)N_NODES * D_FEAT * 2;     // 12.8 MB (bf16)
  const size_t ecap_bytes = (size_t)NBK * CAP * sizeof(int2); // 16.0 MB
  char* ws = (char*)d_ws;
  int4*    xbf  = (int4*)   (ws);                        // 12.8 MB, live whole launch
  int4*    bufA = (int4*)   (ws + hb_bytes);             // h1 (bf16)
  int2*    tmp  = (int2*)   (ws + hb_bytes);             // aliases bufA (build only)
  int4*    bufB = (int4*)   (ws + 2 * hb_bytes);         // h2 (bf16)
  int*     offs = (int*)    (ws + 2 * hb_bytes);         // aliases bufB (build only)
  int2* edges   = (int2*)(ws + 3 * hb_bytes);
  int* row_beg  = (int*) (ws + 3 * hb_bytes + ecap_bytes);
  int* row_end  = (int*) (ws + 3 * hb_bytes + ecap_bytes + 400000);

  const int sblocks = N_NODES / 4;                         // 25000

  // ---- fused convert + bin (1 dispatch), then CSR finalize ----
  convert_bin<<<KBLK + CVB, 1024, 0, stream>>>(
      (const float4*)x, (ushort4*)xbf, erow, ecol, evals, tmp, offs);
  build_csr<<<NBK, 256, 0, stream>>>(tmp, offs, edges, row_beg, row_end);

  // L1: bufA = bf16(A xbf)      (tmp dead after build)
  spmm_wave<<<sblocks, 256, 0, stream>>>(row_beg, row_end, edges, xbf,
                                         bufA, nullptr, nullptr, nullptr, 0);
  // L2: bufB = bf16(A bufA)     (offs dead)
  spmm_wave<<<sblocks, 256, 0, stream>>>(row_beg, row_end, edges, bufA,
                                         bufB, nullptr, nullptr, nullptr, 0);
  // L3: out = A bufB + bufA + bufB   (f32 output)
  spmm_wave<<<sblocks, 256, 0, stream>>>(row_beg, row_end, edges, bufB,
                                         nullptr, (float4*)out, bufA, bufB, 1);
}

// Round 11
// 225.679 us; speedup vs baseline: 1.6170x; 1.0843x over previous
//
#include <hip/hip_runtime.h>

#define N_NODES 100000
#define N_EDGES 1600000
#define D_FEAT  64

#define RSHIFT 8
#define RPB    256                              // rows per bucket
#define NBK    ((N_NODES + RPB - 1) / RPB)      // 391 row-buckets
#define CAP    5120                             // bucket edge capacity (even; 16B-aligned base)
#define EPB    4096                             // edges per bin block
#define KBLK   ((N_EDGES + EPB - 1) / EPB)      // 391 bin blocks
#define OROW   (NBK + 1)
#define CVB    ((N_NODES * D_FEAT / 4 + 1023) / 1024)  // 1563 convert blocks

typedef float f32x2 __attribute__((ext_vector_type(2)));

__device__ __forceinline__ unsigned short f2bf(float f) {
  union { float f; unsigned int i; } v; v.f = f;
  unsigned int b = v.i;
  return (unsigned short)((b + 0x7FFFu + ((b >> 16) & 1u)) >> 16);  // RNE
}
__device__ __forceinline__ float ulo(int u) { return __int_as_float(u << 16); }
__device__ __forceinline__ float uhi(int u) { return __int_as_float(u & 0xFFFF0000); }
__device__ __forceinline__ f32x2 upk(int u) {  // {elem0, elem1} of a bf16 pair
  f32x2 r; r.x = ulo(u); r.y = uhi(u); return r;
}
__device__ __forceinline__ int pk(float a, float b) {
  return (int)f2bf(a) | ((int)f2bf(b) << 16);
}

// ---- fused: blocks [0,KBLK) bin edges; blocks [KBLK, KBLK+CVB) convert x ----
__global__ __launch_bounds__(1024) void convert_bin(
    const float4* __restrict__ xin, ushort4* __restrict__ xout,
    const int* __restrict__ erow, const int* __restrict__ ecol,
    const float* __restrict__ evals, int2* __restrict__ tmp,
    int* __restrict__ offs) {
  __shared__ int hist[NBK];
  __shared__ int sc[NBK];
  int t = threadIdx.x;
  int k = blockIdx.x;
  if (k >= KBLK) {                       // ---- convert path ----
    int i = (k - KBLK) * 1024 + t;
    if (i < N_NODES * D_FEAT / 4) {
      float4 v = xin[i];
      ushort4 o;
      o.x = f2bf(v.x); o.y = f2bf(v.y); o.z = f2bf(v.z); o.w = f2bf(v.w);
      xout[i] = o;
    }
    return;
  }
  // ---- bin path: block-local counting sort of 4096 edges by bucket ----
  if (t < NBK) hist[t] = 0;
  __syncthreads();
  int base = k * EPB;
  int nk = N_EDGES - base; if (nk > EPB) nk = EPB;
  int key[4], vb[4], rk[4], bk[4];
#pragma unroll
  for (int j = 0; j < 4; ++j) {
    int li = j * 1024 + t;
    bk[j] = -1;
    if (li < nk) {
      int e = base + li;
      int r = erow[e];
      key[j] = ((r & (RPB - 1)) << 17) | ecol[e];
      vb[j]  = __float_as_int(evals[e]);
      bk[j]  = r >> RSHIFT;
      rk[j]  = atomicAdd(&hist[bk[j]], 1);
    }
  }
  __syncthreads();
  if (t < NBK) sc[t] = hist[t];
  __syncthreads();
  for (int off = 1; off < NBK; off <<= 1) {
    int u = (t >= off && t < NBK) ? sc[t - off] : 0;
    __syncthreads();
    if (t < NBK) sc[t] += u;
    __syncthreads();
  }
  if (t < NBK) {
    int ex = sc[t] - hist[t];
    sc[t] = ex;
    offs[k * OROW + t] = ex;
  }
  if (t == 0) offs[k * OROW + NBK] = nk;
  __syncthreads();
#pragma unroll
  for (int j = 0; j < 4; ++j) {
    if (bk[j] >= 0) {
      int pos = sc[bk[j]] + rk[j];
      tmp[k * EPB + pos] = make_int2(key[j], vb[j]);
    }
  }
}

// ---- pass 2: octet-per-run sweep. Rows padded to EVEN edge counts so every
// row starts 16B-aligned in the edge array (pad edge = {0,0} adds nothing).
__global__ __launch_bounds__(256) void build_csr(
    const int2* __restrict__ tmp, const int* __restrict__ offs,
    int2* __restrict__ edges, int* __restrict__ row_beg,
    int* __restrict__ row_end) {
  __shared__ int hist[RPB];
  __shared__ int cur[RPB];
  int b = blockIdx.x;
  int t = threadIdx.x;
  int oct = t >> 3;        // 32 octets per block
  int ol  = t & 7;
  hist[t] = 0;
  __syncthreads();
  for (int k = oct; k < KBLK; k += 32) {
    int o0 = offs[k * OROW + b];
    int o1 = offs[k * OROW + b + 1];
    const int2* seg = tmp + k * EPB;
    for (int i = o0 + ol; i < o1; i += 8)
      atomicAdd(&hist[seg[i].x >> 17], 1);
  }
  __syncthreads();
  int v  = hist[t];
  int v2 = (v + 1) & ~1;   // even-padded length
  cur[t] = v2;
  __syncthreads();
  for (int off = 1; off < 256; off <<= 1) {
    int u = (t >= off) ? cur[t - off] : 0;
    __syncthreads();
    cur[t] += u;
    __syncthreads();
  }
  int excl2 = cur[t] - v2;
  int base = b * CAP;
  int gr = b * RPB + t;
  if (gr < N_NODES) {
    row_beg[gr] = base + excl2;
    row_end[gr] = base + excl2 + v;
  }
  if (v & 1) edges[base + excl2 + v] = make_int2(0, 0);  // zero pad slot
  __syncthreads();
  cur[t] = excl2;
  __syncthreads();
  for (int k = oct; k < KBLK; k += 32) {
    int o0 = offs[k * OROW + b];
    int o1 = offs[k * OROW + b + 1];
    const int2* seg = tmp + k * EPB;
    for (int i = o0 + ol; i < o1; i += 8) {
      int2 ed = seg[i];
      int pos = atomicAdd(&cur[ed.x >> 17], 1);
      edges[base + pos] = make_int2(ed.x & 0x1FFFF, ed.y);
    }
  }
}

// ---- SpMM: ONE OCTET PER ROW (8 lanes x int4 = the full 128B feature row).
// 8 rows per wave, zero shuffles, zero LDS. Per edge pair: one int4
// octet-broadcast edge load + two int4 x-gathers; 2-pair unroll for MLP.
__global__ __launch_bounds__(256) void spmm_oct(
    const int* __restrict__ row_beg, const int* __restrict__ row_end,
    const int2* __restrict__ edges, const int4* __restrict__ xq,
    int4* __restrict__ h_q, float4* __restrict__ out,
    const int4* __restrict__ add1, const int4* __restrict__ add2,
    int final_mode) {
  int t = threadIdx.x;
  int lane = t & 63;
  int oct = lane >> 3;     // 0..7: row within wave
  int ol  = lane & 7;      // 0..7: which 16B of the 128B row
  int row = blockIdx.x * 32 + (t >> 6) * 8 + oct;   // grid exact: 3125*32=100000
  int e0 = row_beg[row];
  int e1 = row_end[row];
  const int4* ep = (const int4*)edges + (e0 >> 1);  // e0 even
  // Round UP: odd lengths include the (real, pad) pair; pad {0,0} adds 0.
  int npair = (e1 - e0 + 1) >> 1;
  f32x2 c0 = {0.f, 0.f}, c1 = {0.f, 0.f}, c2 = {0.f, 0.f}, c3 = {0.f, 0.f};

#define PAIR(m) { \
    int4 g0 = xq[(size_t)(m).x * 8 + ol]; \
    int4 g1 = xq[(size_t)(m).z * 8 + ol]; \
    float v0 = __int_as_float((m).y), v1 = __int_as_float((m).w); \
    f32x2 vv0 = {v0, v0}, vv1 = {v1, v1}; \
    c0 += vv0 * upk(g0.x) + vv1 * upk(g1.x); \
    c1 += vv0 * upk(g0.y) + vv1 * upk(g1.y); \
    c2 += vv0 * upk(g0.z) + vv1 * upk(g1.z); \
    c3 += vv0 * upk(g0.w) + vv1 * upk(g1.w); \
  }

  int p = 0;
  for (; p + 2 <= npair; p += 2) {   // 2 pairs = 4 edges: 6 loads in flight
    int4 m0 = ep[p];
    int4 m1 = ep[p + 1];
    PAIR(m0);
    PAIR(m1);
  }
  if (p < npair) {
    int4 m0 = ep[p];
    PAIR(m0);
  }
#undef PAIR

  size_t oi = (size_t)row * 8 + ol;
  if (final_mode) {
    int4 r1 = add1[oi];
    int4 r2 = add2[oi];
    float4 lo, hi;
    lo.x = c0.x + ulo(r1.x) + ulo(r2.x);
    lo.y = c0.y + uhi(r1.x) + uhi(r2.x);
    lo.z = c1.x + ulo(r1.y) + ulo(r2.y);
    lo.w = c1.y + uhi(r1.y) + uhi(r2.y);
    hi.x = c2.x + ulo(r1.z) + ulo(r2.z);
    hi.y = c2.y + uhi(r1.z) + uhi(r2.z);
    hi.z = c3.x + ulo(r1.w) + ulo(r2.w);
    hi.w = c3.y + uhi(r1.w) + uhi(r2.w);
    out[(size_t)row * 16 + ol * 2]     = lo;
    out[(size_t)row * 16 + ol * 2 + 1] = hi;
  } else {
    int4 pq;
    pq.x = pk(c0.x, c0.y);
    pq.y = pk(c1.x, c1.y);
    pq.z = pk(c2.x, c2.y);
    pq.w = pk(c3.x, c3.y);
    h_q[oi] = pq;
  }
}

extern "C" void kernel_launch(void* const* d_in, const int* in_sizes, int n_in,
                              void* d_out, int out_size, void* d_ws, size_t ws_size,
                              hipStream_t stream) {
  const float* x     = (const float*)d_in[0];
  const int*   erow  = (const int*)d_in[1];
  const int*   ecol  = (const int*)d_in[2];
  const float* evals = (const float*)d_in[3];
  float* out = (float*)d_out;

  const size_t hb_bytes   = (size_t)N_NODES * D_FEAT * 2;     // 12.8 MB (bf16)
  const size_t ecap_bytes = (size_t)NBK * CAP * sizeof(int2); // 16.0 MB
  char* ws = (char*)d_ws;
  int4*    xbf  = (int4*)   (ws);                        // 12.8 MB, live whole launch
  int4*    bufA = (int4*)   (ws + hb_bytes);             // h1 (bf16)
  int2*    tmp  = (int2*)   (ws + hb_bytes);             // aliases bufA (build only)
  int4*    bufB = (int4*)   (ws + 2 * hb_bytes);         // h2 (bf16)
  int*     offs = (int*)    (ws + 2 * hb_bytes);         // aliases bufB (build only)
  int2* edges   = (int2*)(ws + 3 * hb_bytes);
  int* row_beg  = (int*) (ws + 3 * hb_bytes + ecap_bytes);
  int* row_end  = (int*) (ws + 3 * hb_bytes + ecap_bytes + 400000);

  const int sblocks = N_NODES / 32;                        // 3125 (8 rows/wave)

  // ---- fused convert + bin (1 dispatch), then CSR finalize ----
  convert_bin<<<KBLK + CVB, 1024, 0, stream>>>(
      (const float4*)x, (ushort4*)xbf, erow, ecol, evals, tmp, offs);
  build_csr<<<NBK, 256, 0, stream>>>(tmp, offs, edges, row_beg, row_end);

  // L1: bufA = bf16(A xbf)      (tmp dead after build)
  spmm_oct<<<sblocks, 256, 0, stream>>>(row_beg, row_end, edges, xbf,
                                        bufA, nullptr, nullptr, nullptr, 0);
  // L2: bufB = bf16(A bufA)     (offs dead)
  spmm_oct<<<sblocks, 256, 0, stream>>>(row_beg, row_end, edges, bufA,
                                        bufB, nullptr, nullptr, nullptr, 0);
  // L3: out = A bufB + bufA + bufB   (f32 output)
  spmm_oct<<<sblocks, 256, 0, stream>>>(row_beg, row_end, edges, bufB,
                                        nullptr, (float4*)out, bufA, bufB, 1);
}